// Round 1
// baseline (479.820 us; speedup 1.0000x reference)
//
#include <hip/hip_runtime.h>

// CvT block, MI355X bf16-MFMA implementation.
// B=32, C=128, L=32 (seq=1024), H=8, DK=64, HD=512, NLAYER=4.

#define NB   32
#define NH   8
#define SEQ  1024
#define DKH  64
#define HDIM 512
#define CIN  128

typedef __bf16 bf16x8 __attribute__((ext_vector_type(8)));
typedef float floatx4 __attribute__((ext_vector_type(4)));
typedef unsigned short u16x8 __attribute__((ext_vector_type(8)));

__device__ __forceinline__ unsigned short f2bf(float f) {
    union { float f; unsigned int u; } c; c.f = f;
    unsigned int u = c.u;
    return (unsigned short)((u + 0x7fffu + ((u >> 16) & 1u)) >> 16); // RNE
}
__device__ __forceinline__ float bf2f(unsigned short h) {
    union { unsigned int u; float f; } c; c.u = ((unsigned int)h) << 16; return c.f;
}
__device__ __forceinline__ bf16x8 ldfrag(const unsigned short* p) {
    u16x8 v = *reinterpret_cast<const u16x8*>(p);
    return __builtin_bit_cast(bf16x8, v);
}

// ---------------- prep kernels ----------------

// wqkvb rows: 0-511 Wq*0.125 (fold 1/sqrt(dk)), 512-1023 Wk, 1024-1535 Wv. Plus W0 cast.
__global__ __launch_bounds__(256) void prep_w(const float* __restrict__ Wq,
                                              const float* __restrict__ Wk,
                                              const float* __restrict__ Wv,
                                              const float* __restrict__ W0,
                                              unsigned short* __restrict__ wqkvb,
                                              unsigned short* __restrict__ w0b) {
    int idx = blockIdx.x * 256 + threadIdx.x;  // 262144 total
    if (idx < 196608) {
        int row = idx >> 7;
        float v;
        if (row < 512)       v = Wq[idx] * 0.125f;
        else if (row < 1024) v = Wk[idx - 65536];
        else                 v = Wv[idx - 131072];
        wqkvb[idx] = f2bf(v);
    } else {
        int j = idx - 196608;  // 65536 elems of W0 (c, hd) row-major
        w0b[j] = f2bf(W0[j]);
    }
}

// biasx[h][i][j] = R[h][(i1-i2)%32][(j1-j2)%32] * 0.125 (bias is scaled by 1/sqrt(dk) too)
__global__ __launch_bounds__(256) void prep_bias(const float* __restrict__ R,
                                                 unsigned short* __restrict__ biasx) {
    int idx = blockIdx.x * 256 + threadIdx.x;  // 8388608 total
    int j = idx & 1023, i = (idx >> 10) & 1023, h = idx >> 20;
    int dx = ((i >> 5) - (j >> 5)) & 31;
    int dy = ((i & 31) - (j & 31)) & 31;
    biasx[idx] = f2bf(R[(h << 10) + (dx << 5) + dy] * 0.125f);
}

// xt[b][pos][c] = x[b][c][pos] * inv_layer, bf16.  64x64 LDS tile transpose.
__global__ __launch_bounds__(256) void prep_xt(const float* __restrict__ x,
                                               unsigned short* __restrict__ xt) {
    __shared__ float lds[64 * 65];
    int b = blockIdx.x, c0 = blockIdx.y * 64, p0 = blockIdx.z * 64;
    int t = threadIdx.x, tr = t >> 6, tc = t & 63;
    const float inv_layer = 0.44721359549995793f;  // 1/sqrt(5)
    for (int rr = 0; rr < 16; ++rr) {
        int cl = rr * 4 + tr;
        lds[cl * 65 + tc] = x[(b * CIN + c0 + cl) * SEQ + p0 + tc];
    }
    __syncthreads();
    for (int rr = 0; rr < 16; ++rr) {
        int pl = rr * 4 + tr;
        xt[(b * SEQ + p0 + pl) * CIN + c0 + tc] = f2bf(lds[tc * 65 + pl] * inv_layer);
    }
}

// ---------------- QKV projection ----------------

// Q,K: transposed orientation D[m=pos][n=wrow].  A = xt (pos,c), B = wqkv (wrow,c).
// Writes Qt/Kt as (b,h,pos,d).  Qt already has 0.125 folded via Wq.
__global__ __launch_bounds__(256) void qk_gemm(const unsigned short* __restrict__ xt,
                                               const unsigned short* __restrict__ wqkv,
                                               unsigned short* __restrict__ Qt,
                                               unsigned short* __restrict__ Kt) {
    int b = blockIdx.x, pt = blockIdx.y, wt = blockIdx.z;
    int tid = threadIdx.x, wave = tid >> 6, lane = tid & 63, q = lane >> 4, n = lane & 15;
    int pos0 = pt * 64 + wave * 16;
    int wrow0 = wt * 64;  // in [0,1024): Q rows then K rows
    const unsigned short* xrow = xt + (b * SEQ + pos0 + n) * CIN;
    floatx4 acc[4];
    for (int s = 0; s < 4; ++s) acc[s] = (floatx4){0.f, 0.f, 0.f, 0.f};
    for (int kc = 0; kc < 4; ++kc) {
        bf16x8 a = ldfrag(xrow + kc * 32 + q * 8);
        for (int s = 0; s < 4; ++s) {
            bf16x8 bw = ldfrag(wqkv + (wrow0 + 16 * s + n) * CIN + kc * 32 + q * 8);
            acc[s] = __builtin_amdgcn_mfma_f32_16x16x32_bf16(a, bw, acc[s], 0, 0, 0);
        }
    }
    for (int s = 0; s < 4; ++s) {
        int wrow = wrow0 + 16 * s + n;
        int d = wrow & 63;
        for (int r = 0; r < 4; ++r) {
            int pos = pos0 + 4 * q + r;
            unsigned short v = f2bf(acc[s][r]);
            if (wrow < 512) Qt[((b * NH + (wrow >> 6)) * SEQ + pos) * DKH + d] = v;
            else            Kt[((b * NH + ((wrow >> 6) - 8)) * SEQ + pos) * DKH + d] = v;
        }
    }
}

// V: normal orientation D[m=vrow][n=pos].  A = wqkv V-rows (vrow,c), B = xt (pos,c).
// Writes Vt as (b,h,d,pos).
__global__ __launch_bounds__(256) void v_gemm(const unsigned short* __restrict__ xt,
                                              const unsigned short* __restrict__ wqkv,
                                              unsigned short* __restrict__ Vt) {
    int b = blockIdx.x, vt = blockIdx.y, pt = blockIdx.z;
    int tid = threadIdx.x, wave = tid >> 6, lane = tid & 63, q = lane >> 4, n = lane & 15;
    int vrow0 = vt * 64 + wave * 16;  // in [0,512)
    int pos0 = pt * 64;
    const unsigned short* wrowp = wqkv + (1024 + vrow0 + n) * CIN;
    floatx4 acc[4];
    for (int s = 0; s < 4; ++s) acc[s] = (floatx4){0.f, 0.f, 0.f, 0.f};
    for (int kc = 0; kc < 4; ++kc) {
        bf16x8 a = ldfrag(wrowp + kc * 32 + q * 8);
        for (int s = 0; s < 4; ++s) {
            bf16x8 bx = ldfrag(xt + (b * SEQ + pos0 + 16 * s + n) * CIN + kc * 32 + q * 8);
            acc[s] = __builtin_amdgcn_mfma_f32_16x16x32_bf16(a, bx, acc[s], 0, 0, 0);
        }
    }
    for (int s = 0; s < 4; ++s) {
        int pos = pos0 + 16 * s + n;
        for (int r = 0; r < 4; ++r) {
            int vrow = vrow0 + 4 * q + r;
            Vt[((b * NH + (vrow >> 6)) * DKH + (vrow & 63)) * SEQ + pos] = f2bf(acc[s][r]);
        }
    }
}

// ---------------- flash attention ----------------
// WG = (b, h, 64-query block); 4 waves x 16 queries each.  Key tiles of 64.
// att output layout: (b, i, h*64+d) bf16 (K-major for the final GEMM).
__global__ __launch_bounds__(256) void attn_kernel(const unsigned short* __restrict__ Qt,
                                                   const unsigned short* __restrict__ Kt,
                                                   const unsigned short* __restrict__ Vt,
                                                   const unsigned short* __restrict__ biasx,
                                                   unsigned short* __restrict__ att) {
    __shared__ alignas(16) unsigned short lds_k[64 * 72];   // (j_local, d), stride 72
    __shared__ alignas(16) unsigned short lds_v[64 * 72];   // (d, j_local), stride 72
    __shared__ alignas(16) unsigned short lds_p[4][16 * 72];// per-wave P (i_local, j_local)

    int gid = blockIdx.x;
    int qb = gid & 15, h = (gid >> 4) & 7, b = gid >> 7;
    int tid = threadIdx.x, wave = tid >> 6, lane = tid & 63, q = lane >> 4, n = lane & 15;
    int i0 = qb * 64 + wave * 16;
    int bh = b * NH + h;

    const unsigned short* qbase = Qt + bh * SEQ * DKH;
    const unsigned short* kbase = Kt + bh * SEQ * DKH;
    const unsigned short* vbase = Vt + bh * DKH * SEQ;
    const unsigned short* bbase = biasx + h * SEQ * SEQ;

    bf16x8 aq0 = ldfrag(qbase + (i0 + n) * DKH + 0 + q * 8);
    bf16x8 aq1 = ldfrag(qbase + (i0 + n) * DKH + 32 + q * 8);

    float m_i[4], l_i[4];
    floatx4 o[4];
    for (int r = 0; r < 4; ++r) { m_i[r] = -1e30f; l_i[r] = 0.f; }
    for (int u = 0; u < 4; ++u) o[u] = (floatx4){0.f, 0.f, 0.f, 0.f};

    int srow = tid >> 2, sseg = tid & 3;  // staging: 64 rows x 4 16-elem segs

    for (int kt = 0; kt < 16; ++kt) {
        int j0 = kt * 64;
        __syncthreads();  // prior PV done before overwriting K/V tiles
        {
            const unsigned short* ks = kbase + (j0 + srow) * DKH + sseg * 16;
            u16x8 k0 = *(const u16x8*)ks;
            u16x8 k1 = *(const u16x8*)(ks + 8);
            *(u16x8*)&lds_k[srow * 72 + sseg * 16] = k0;
            *(u16x8*)&lds_k[srow * 72 + sseg * 16 + 8] = k1;
            const unsigned short* vs = vbase + srow * SEQ + j0 + sseg * 16;
            u16x8 v0 = *(const u16x8*)vs;
            u16x8 v1 = *(const u16x8*)(vs + 8);
            *(u16x8*)&lds_v[srow * 72 + sseg * 16] = v0;
            *(u16x8*)&lds_v[srow * 72 + sseg * 16 + 8] = v1;
        }
        __syncthreads();

        // S = (0.125 Q) K^T + 0.125*bias  -- 16 queries x 64 keys per wave
        floatx4 sv[4];
        for (int s = 0; s < 4; ++s) {
            floatx4 acc = (floatx4){0.f, 0.f, 0.f, 0.f};
            bf16x8 bk0 = ldfrag(&lds_k[(16 * s + n) * 72 + 0 + q * 8]);
            acc = __builtin_amdgcn_mfma_f32_16x16x32_bf16(aq0, bk0, acc, 0, 0, 0);
            bf16x8 bk1 = ldfrag(&lds_k[(16 * s + n) * 72 + 32 + q * 8]);
            acc = __builtin_amdgcn_mfma_f32_16x16x32_bf16(aq1, bk1, acc, 0, 0, 0);
            sv[s] = acc;
        }
        for (int s = 0; s < 4; ++s)
            for (int r = 0; r < 4; ++r)
                sv[s][r] += bf2f(bbase[(i0 + 4 * q + r) * SEQ + j0 + 16 * s + n]);

        // online softmax (rows 4q+r live in lanes 16q..16q+15)
        for (int r = 0; r < 4; ++r) {
            float mt = fmaxf(fmaxf(sv[0][r], sv[1][r]), fmaxf(sv[2][r], sv[3][r]));
            for (int off = 8; off >= 1; off >>= 1) mt = fmaxf(mt, __shfl_xor(mt, off, 16));
            float mnew = fmaxf(m_i[r], mt);
            float alpha = __expf(m_i[r] - mnew);
            float rs = 0.f;
            for (int s = 0; s < 4; ++s) {
                float p = __expf(sv[s][r] - mnew);
                sv[s][r] = p; rs += p;
            }
            for (int off = 8; off >= 1; off >>= 1) rs += __shfl_xor(rs, off, 16);
            l_i[r] = l_i[r] * alpha + rs;
            m_i[r] = mnew;
            for (int u = 0; u < 4; ++u) o[u][r] *= alpha;
        }
        // P -> LDS (C-layout rows 4q+r  ->  row-major (i_local, j_local))
        for (int s = 0; s < 4; ++s)
            for (int r = 0; r < 4; ++r)
                lds_p[wave][(4 * q + r) * 72 + 16 * s + n] = f2bf(sv[s][r]);
        __syncthreads();

        // O += P V   (A = P from LDS, B = V (d,j) from LDS)
        bf16x8 ap0 = ldfrag(&lds_p[wave][n * 72 + 0 + q * 8]);
        bf16x8 ap1 = ldfrag(&lds_p[wave][n * 72 + 32 + q * 8]);
        for (int u = 0; u < 4; ++u) {
            bf16x8 bv0 = ldfrag(&lds_v[(16 * u + n) * 72 + 0 + q * 8]);
            o[u] = __builtin_amdgcn_mfma_f32_16x16x32_bf16(ap0, bv0, o[u], 0, 0, 0);
            bf16x8 bv1 = ldfrag(&lds_v[(16 * u + n) * 72 + 32 + q * 8]);
            o[u] = __builtin_amdgcn_mfma_f32_16x16x32_bf16(ap1, bv1, o[u], 0, 0, 0);
        }
    }

    for (int r = 0; r < 4; ++r) {
        float inv = 1.0f / l_i[r];
        int i = i0 + 4 * q + r;
        for (int u = 0; u < 4; ++u)
            att[(b * SEQ + i) * HDIM + h * DKH + 16 * u + n] = f2bf(o[u][r] * inv);
    }
}

// ---------------- output projection + residual ----------------
__global__ __launch_bounds__(256) void out_gemm(const unsigned short* __restrict__ att,
                                                const unsigned short* __restrict__ w0b,
                                                const float* __restrict__ x,
                                                float* __restrict__ out) {
    int b = blockIdx.x, ct = blockIdx.y, it = blockIdx.z;
    int tid = threadIdx.x, wave = tid >> 6, lane = tid & 63, q = lane >> 4, n = lane & 15;
    int c0 = ct * 64 + wave * 16;
    int i0 = it * 64;
    floatx4 acc[4];
    for (int s = 0; s < 4; ++s) acc[s] = (floatx4){0.f, 0.f, 0.f, 0.f};
    for (int kc = 0; kc < 16; ++kc) {
        bf16x8 a = ldfrag(w0b + (c0 + n) * HDIM + kc * 32 + q * 8);
        for (int s = 0; s < 4; ++s) {
            bf16x8 bt = ldfrag(att + (b * SEQ + i0 + 16 * s + n) * HDIM + kc * 32 + q * 8);
            acc[s] = __builtin_amdgcn_mfma_f32_16x16x32_bf16(a, bt, acc[s], 0, 0, 0);
        }
    }
    for (int s = 0; s < 4; ++s)
        for (int r = 0; r < 4; ++r) {
            int idx = (b * CIN + c0 + 4 * q + r) * SEQ + i0 + 16 * s + n;
            out[idx] = acc[s][r] + x[idx];
        }
}

// ---------------- launch ----------------
extern "C" void kernel_launch(void* const* d_in, const int* in_sizes, int n_in,
                              void* d_out, int out_size, void* d_ws, size_t ws_size,
                              hipStream_t stream) {
    const float* x  = (const float*)d_in[0];
    const float* Wq = (const float*)d_in[1];
    const float* Wk = (const float*)d_in[2];
    const float* Wv = (const float*)d_in[3];
    const float* R  = (const float*)d_in[4];
    const float* W0 = (const float*)d_in[5];
    float* out = (float*)d_out;

    char* ws = (char*)d_ws;
    size_t off = 0;
    unsigned short* Qt    = (unsigned short*)(ws + off); off += (size_t)NB * NH * SEQ * DKH * 2;  // 33.5MB
    unsigned short* Kt    = (unsigned short*)(ws + off); off += (size_t)NB * NH * SEQ * DKH * 2;
    unsigned short* Vt    = (unsigned short*)(ws + off); off += (size_t)NB * NH * SEQ * DKH * 2;
    unsigned short* att   = (unsigned short*)(ws + off); off += (size_t)NB * SEQ * HDIM * 2;
    unsigned short* xt    = (unsigned short*)(ws + off); off += (size_t)NB * SEQ * CIN * 2;
    unsigned short* wqkvb = (unsigned short*)(ws + off); off += (size_t)1536 * 128 * 2;
    unsigned short* w0b   = (unsigned short*)(ws + off); off += (size_t)128 * 512 * 2;
    unsigned short* biasx = (unsigned short*)(ws + off); off += (size_t)NH * SEQ * SEQ * 2;      // 16.8MB
    (void)ws_size; (void)in_sizes; (void)n_in; (void)out_size;

    prep_w<<<1024, 256, 0, stream>>>(Wq, Wk, Wv, W0, wqkvb, w0b);
    prep_bias<<<32768, 256, 0, stream>>>(R, biasx);
    prep_xt<<<dim3(NB, 2, 16), 256, 0, stream>>>(x, xt);
    qk_gemm<<<dim3(NB, 16, 16), 256, 0, stream>>>(xt, wqkvb, Qt, Kt);
    v_gemm<<<dim3(NB, 8, 16), 256, 0, stream>>>(xt, wqkvb, Vt);
    attn_kernel<<<NB * NH * 16, 256, 0, stream>>>(Qt, Kt, Vt, biasx, att);
    out_gemm<<<dim3(NB, 2, 16), 256, 0, stream>>>(att, w0b, x, out);
}